// Round 7
// baseline (1241.499 us; speedup 1.0000x reference)
//
#include <hip/hip_runtime.h>
#include <hip/hip_cooperative_groups.h>
#include <math.h>

namespace cg = cooperative_groups;

#define MN 1537          // M_NODES
#define NFFT 4096
#define CW 0.06283185307179587f      // 2*pi*h
#define W4096 1.5339807878856412e-3f // 2*pi/4096

__device__ __forceinline__ float2 cmulf(float2 a, float2 b) {
    return make_float2(a.x*b.x - a.y*b.y, a.x*b.y + a.y*b.x);
}
__device__ __forceinline__ float2 cadd(float2 a, float2 b){ return make_float2(a.x+b.x, a.y+b.y); }
__device__ __forceinline__ float2 csub(float2 a, float2 b){ return make_float2(a.x-b.x, a.y-b.y); }
__device__ __forceinline__ float2 mulnegi(float2 z){ return make_float2(z.y, -z.x); }  // z * (-i)
__device__ __forceinline__ float2 mulposi(float2 z){ return make_float2(-z.y, z.x); }  // z * (+i)
__device__ __forceinline__ float2 cconj(float2 z){ return make_float2(z.x, -z.y); }
// XOR bank swizzle: bijective on [0,4096); per-wave bank-pair uniform (4-way min)
// for all stride classes {1,8,64,512} used by the radix-8 stages.
__device__ __forceinline__ int SW(int i){ return i ^ ((i >> 3) & 15); }

__device__ __forceinline__ float ws_at(int k) {
    float xi = 0.01f * (float)(k - 768);
    float t  = 0.31415926535897931f * xi;      // pi*ell*xi
    float S  = 0.25066282746310002f * expf(-2.0f * t * t); // sqrt(2pi)*ell
    return sqrtf(0.01f * S);
}

// cached twiddle quintet for one fused stage-triple
struct Tw { float2 w1, w2, w4, c1, c3; };

__device__ __forceinline__ Tw make_tw(float ang){
    Tw t;
    __sincosf(ang, &t.w1.y, &t.w1.x);
    t.w2 = cmulf(t.w1, t.w1);
    t.w4 = cmulf(t.w2, t.w2);
    const float R = 0.70710678118654752f;
    t.c1 = cmulf(t.w1, make_float2( R, -R));   // w1 * e^{-i pi/4}
    t.c3 = cmulf(t.w1, make_float2(-R, -R));   // w1 * e^{-i 3pi/4}
    return t;
}

// ---------------- forward DIF triple (stages S, S-1, S-2), cached twiddles
template<int S>
__device__ __forceinline__ void fwd8c(float2* fb, int tt, const Tw& w){
    const int Q = 1 << (S-2);
    const int p = tt & (Q-1);
    const int g = tt >> (S-2);
    const int base = (g << (S+1)) + p;
    float2 a0 = fb[SW(base      )], a1 = fb[SW(base +   Q)];
    float2 a2 = fb[SW(base + 2*Q)], a3 = fb[SW(base + 3*Q)];
    float2 a4 = fb[SW(base + 4*Q)], a5 = fb[SW(base + 5*Q)];
    float2 a6 = fb[SW(base + 6*Q)], a7 = fb[SW(base + 7*Q)];
    float2 b0 = cadd(a0,a4), b1 = cadd(a1,a5), b2 = cadd(a2,a6), b3 = cadd(a3,a7);
    float2 b4 = cmulf(csub(a0,a4), w.w1);
    float2 b5 = cmulf(csub(a1,a5), w.c1);
    float2 b6 = mulnegi(cmulf(csub(a2,a6), w.w1));
    float2 b7 = cmulf(csub(a3,a7), w.c3);
    float2 c0 = cadd(b0,b2), c2 = cmulf(csub(b0,b2), w.w2);
    float2 c1 = cadd(b1,b3), c3 = mulnegi(cmulf(csub(b1,b3), w.w2));
    float2 c4 = cadd(b4,b6), c6 = cmulf(csub(b4,b6), w.w2);
    float2 c5 = cadd(b5,b7), c7 = mulnegi(cmulf(csub(b5,b7), w.w2));
    fb[SW(base      )] = cadd(c0,c1);
    fb[SW(base +   Q)] = cmulf(csub(c0,c1), w.w4);
    fb[SW(base + 2*Q)] = cadd(c2,c3);
    fb[SW(base + 3*Q)] = cmulf(csub(c2,c3), w.w4);
    fb[SW(base + 4*Q)] = cadd(c4,c5);
    fb[SW(base + 5*Q)] = cmulf(csub(c4,c5), w.w4);
    fb[SW(base + 6*Q)] = cadd(c6,c7);
    fb[SW(base + 7*Q)] = cmulf(csub(c6,c7), w.w4);
}

// ---------------- inverse DIT triple (stages S, S+1, S+2), twiddles = conj(cached)
template<int S>
__device__ __forceinline__ void inv8c(float2* fb, int tt, const Tw& w){
    const int Q = 1 << S;
    const int p = tt & (Q-1);
    const int g = tt >> S;
    const int base = (g << (S+3)) + p;
    float2 u1 = cconj(w.w1), u2 = cconj(w.w2), u4 = cconj(w.w4);
    float2 uc1 = cconj(w.c1), uc3 = cconj(w.c3);
    float2 a0 = fb[SW(base      )], a1 = fb[SW(base +   Q)];
    float2 a2 = fb[SW(base + 2*Q)], a3 = fb[SW(base + 3*Q)];
    float2 a4 = fb[SW(base + 4*Q)], a5 = fb[SW(base + 5*Q)];
    float2 a6 = fb[SW(base + 6*Q)], a7 = fb[SW(base + 7*Q)];
    float2 m;
    m = cmulf(a1, u4); float2 t0 = cadd(a0,m), t1 = csub(a0,m);
    m = cmulf(a3, u4); float2 t2 = cadd(a2,m), t3 = csub(a2,m);
    m = cmulf(a5, u4); float2 t4 = cadd(a4,m), t5 = csub(a4,m);
    m = cmulf(a7, u4); float2 t6 = cadd(a6,m), t7 = csub(a6,m);
    m = cmulf(t2, u2);          float2 e0 = cadd(t0,m), e2 = csub(t0,m);
    m = mulposi(cmulf(t3, u2)); float2 e1 = cadd(t1,m), e3 = csub(t1,m);
    m = cmulf(t6, u2);          float2 e4 = cadd(t4,m), e6 = csub(t4,m);
    m = mulposi(cmulf(t7, u2)); float2 e5 = cadd(t5,m), e7 = csub(t5,m);
    m = cmulf(e4, u1);          fb[SW(base      )] = cadd(e0,m); fb[SW(base + 4*Q)] = csub(e0,m);
    m = cmulf(e5, uc1);         fb[SW(base +   Q)] = cadd(e1,m); fb[SW(base + 5*Q)] = csub(e1,m);
    m = mulposi(cmulf(e6, u1)); fb[SW(base + 2*Q)] = cadd(e2,m); fb[SW(base + 6*Q)] = csub(e2,m);
    m = cmulf(e7, uc3);         fb[SW(base + 3*Q)] = cadd(e3,m); fb[SW(base + 7*Q)] = csub(e3,m);
}

// stage-11 triple, inputs from registers (slots tt+s*512; s>=4 are zero)
__device__ __forceinline__ void fwd8_first(float2* fb, int tt, const Tw& w, const float2* in){
    float2 b0 = in[0], b1 = in[1], b2 = in[2], b3 = in[3];
    float2 b4 = cmulf(in[0], w.w1);
    float2 b5 = cmulf(in[1], w.c1);
    float2 b6 = mulnegi(cmulf(in[2], w.w1));
    float2 b7 = cmulf(in[3], w.c3);
    float2 c0 = cadd(b0,b2), c2 = cmulf(csub(b0,b2), w.w2);
    float2 c1 = cadd(b1,b3), c3 = mulnegi(cmulf(csub(b1,b3), w.w2));
    float2 c4 = cadd(b4,b6), c6 = cmulf(csub(b4,b6), w.w2);
    float2 c5 = cadd(b5,b7), c7 = mulnegi(cmulf(csub(b5,b7), w.w2));
    fb[SW(tt       )] = cadd(c0,c1);
    fb[SW(tt +  512)] = cmulf(csub(c0,c1), w.w4);
    fb[SW(tt + 1024)] = cadd(c2,c3);
    fb[SW(tt + 1536)] = cmulf(csub(c2,c3), w.w4);
    fb[SW(tt + 2048)] = cadd(c4,c5);
    fb[SW(tt + 2560)] = cmulf(csub(c4,c5), w.w4);
    fb[SW(tt + 3072)] = cadd(c6,c7);
    fb[SW(tt + 3584)] = cmulf(csub(c6,c7), w.w4);
}

// inverse stage-9 triple returning only slots tt+s*512 (s=0..3) in registers
__device__ __forceinline__ void inv8_last(const float2* fb, int tt, const Tw& w, float2* outv){
    float2 u1 = cconj(w.w1), u2 = cconj(w.w2), u4 = cconj(w.w4);
    float2 uc1 = cconj(w.c1), uc3 = cconj(w.c3);
    float2 a0 = fb[SW(tt       )], a1 = fb[SW(tt +  512)];
    float2 a2 = fb[SW(tt + 1024)], a3 = fb[SW(tt + 1536)];
    float2 a4 = fb[SW(tt + 2048)], a5 = fb[SW(tt + 2560)];
    float2 a6 = fb[SW(tt + 3072)], a7 = fb[SW(tt + 3584)];
    float2 m;
    m = cmulf(a1, u4); float2 t0 = cadd(a0,m), t1 = csub(a0,m);
    m = cmulf(a3, u4); float2 t2 = cadd(a2,m), t3 = csub(a2,m);
    m = cmulf(a5, u4); float2 t4 = cadd(a4,m), t5 = csub(a4,m);
    m = cmulf(a7, u4); float2 t6 = cadd(a6,m), t7 = csub(a6,m);
    m = cmulf(t2, u2);          float2 e0 = cadd(t0,m), e2 = csub(t0,m);
    m = mulposi(cmulf(t3, u2)); float2 e1 = cadd(t1,m), e3 = csub(t1,m);
    m = cmulf(t6, u2);          float2 e4 = cadd(t4,m), e6 = csub(t4,m);
    m = mulposi(cmulf(t7, u2)); float2 e5 = cadd(t5,m), e7 = csub(t5,m);
    outv[0] = cadd(e0, cmulf(e4, u1));
    outv[1] = cadd(e1, cmulf(e5, uc1));
    outv[2] = cadd(e2, mulposi(cmulf(e6, u1)));
    outv[3] = cadd(e3, cmulf(e7, uc3));
}

// fused middle: fwd triple S=2 (identity tw) + pointwise*g + inv triple S=0,
// entirely in registers; touches contiguous slots 8*tt..8*tt+7
__device__ __forceinline__ void mid8(float2* fb, int tt, const float2* g){
    const float R = 0.70710678118654752f;
    const int base = tt << 3;
    float2 a0 = fb[SW(base  )], a1 = fb[SW(base+1)];
    float2 a2 = fb[SW(base+2)], a3 = fb[SW(base+3)];
    float2 a4 = fb[SW(base+4)], a5 = fb[SW(base+5)];
    float2 a6 = fb[SW(base+6)], a7 = fb[SW(base+7)];
    float2 b0 = cadd(a0,a4), b1 = cadd(a1,a5), b2 = cadd(a2,a6), b3 = cadd(a3,a7);
    float2 b4 = csub(a0,a4);
    float2 b5 = cmulf(csub(a1,a5), make_float2( R, -R));
    float2 b6 = mulnegi(csub(a2,a6));
    float2 b7 = cmulf(csub(a3,a7), make_float2(-R, -R));
    float2 c0 = cadd(b0,b2), c2 = csub(b0,b2);
    float2 c1 = cadd(b1,b3), c3 = mulnegi(csub(b1,b3));
    float2 c4 = cadd(b4,b6), c6 = csub(b4,b6);
    float2 c5 = cadd(b5,b7), c7 = mulnegi(csub(b5,b7));
    float2 d0 = cadd(c0,c1), d1 = csub(c0,c1);
    float2 d2 = cadd(c2,c3), d3 = csub(c2,c3);
    float2 d4 = cadd(c4,c5), d5 = csub(c4,c5);
    float2 d6 = cadd(c6,c7), d7 = csub(c6,c7);
    d0 = cmulf(d0, g[0]); d1 = cmulf(d1, g[1]); d2 = cmulf(d2, g[2]); d3 = cmulf(d3, g[3]);
    d4 = cmulf(d4, g[4]); d5 = cmulf(d5, g[5]); d6 = cmulf(d6, g[6]); d7 = cmulf(d7, g[7]);
    float2 m;
    m = d1; float2 t0 = cadd(d0,m), t1 = csub(d0,m);
    m = d3; float2 t2 = cadd(d2,m), t3 = csub(d2,m);
    m = d5; float2 t4 = cadd(d4,m), t5 = csub(d4,m);
    m = d7; float2 t6 = cadd(d6,m), t7 = csub(d6,m);
    m = t2;          float2 e0 = cadd(t0,m), e2 = csub(t0,m);
    m = mulposi(t3); float2 e1 = cadd(t1,m), e3 = csub(t1,m);
    m = t6;          float2 e4 = cadd(t4,m), e6 = csub(t4,m);
    m = mulposi(t7); float2 e5 = cadd(t5,m), e7 = csub(t5,m);
    m = e4;                           fb[SW(base  )] = cadd(e0,m); fb[SW(base+4)] = csub(e0,m);
    m = cmulf(e5, make_float2(R, R)); fb[SW(base+1)] = cadd(e1,m); fb[SW(base+5)] = csub(e1,m);
    m = mulposi(e6);                  fb[SW(base+2)] = cadd(e2,m); fb[SW(base+6)] = csub(e2,m);
    m = cmulf(e7, make_float2(-R, R));fb[SW(base+3)] = cadd(e3,m); fb[SW(base+7)] = csub(e3,m);
}

// fwd S=2 triple with register outputs only (for G spectrum capture)
__device__ __forceinline__ void fwd8_last_reg(const float2* fb, int tt, float2* gout){
    const float R = 0.70710678118654752f;
    const int base = tt << 3;
    float2 a0 = fb[SW(base  )], a1 = fb[SW(base+1)];
    float2 a2 = fb[SW(base+2)], a3 = fb[SW(base+3)];
    float2 a4 = fb[SW(base+4)], a5 = fb[SW(base+5)];
    float2 a6 = fb[SW(base+6)], a7 = fb[SW(base+7)];
    float2 b0 = cadd(a0,a4), b1 = cadd(a1,a5), b2 = cadd(a2,a6), b3 = cadd(a3,a7);
    float2 b4 = csub(a0,a4);
    float2 b5 = cmulf(csub(a1,a5), make_float2( R, -R));
    float2 b6 = mulnegi(csub(a2,a6));
    float2 b7 = cmulf(csub(a3,a7), make_float2(-R, -R));
    float2 c0 = cadd(b0,b2), c2 = csub(b0,b2);
    float2 c1 = cadd(b1,b3), c3 = mulnegi(csub(b1,b3));
    float2 c4 = cadd(b4,b6), c6 = csub(b4,b6);
    float2 c5 = cadd(b5,b7), c7 = mulnegi(csub(b5,b7));
    gout[0] = cadd(c0,c1); gout[1] = csub(c0,c1);
    gout[2] = cadd(c2,c3); gout[3] = csub(c2,c3);
    gout[4] = cadd(c4,c5); gout[5] = csub(c4,c5);
    gout[6] = cadd(c6,c7); gout[7] = csub(c6,c7);
}

// circular convolution; result scaled by 4096
__device__ __forceinline__ void conv_fft(float2* fb, const float2* g, int tt,
                                         const Tw& T11, const Tw& T8, const Tw& T5,
                                         const float2* in, float2* outv){
    __syncthreads();                       // prior reads of fb done
    fwd8_first(fb, tt, T11, in); __syncthreads();
    fwd8c<8>(fb, tt, T8); __syncthreads();
    fwd8c<5>(fb, tt, T5); __syncthreads();
    mid8(fb, tt, g);      __syncthreads();
    inv8c<3>(fb, tt, T5); __syncthreads();
    inv8c<6>(fb, tt, T8); __syncthreads();
    inv8_last(fb, tt, T11, outv);
}

// half-block (512-thread) dual reduction; scratch = dead FFT slots:
// wave w's lane0 writes fbh[SW(64*w)] — a slot only that same lane read in
// inv8_last (64*w = tt+512k only for tt=64*w, k=0) → race-free without an
// entry barrier. Both halves call in lockstep (same __syncthreads counts).
__device__ __forceinline__ float2 hreduce2(float2 v, float2* fbh, int tt){
    int lane = tt & 63, w8 = tt >> 6;
    #pragma unroll
    for (int off = 32; off > 0; off >>= 1){
        v.x += __shfl_down(v.x, off, 64);
        v.y += __shfl_down(v.y, off, 64);
    }
    if (lane == 0) fbh[SW(64*w8)] = v;
    __syncthreads();
    if (w8 == 0){
        float2 s = (lane < 8) ? fbh[SW(64*lane)] : make_float2(0.f, 0.f);
        #pragma unroll
        for (int off = 4; off > 0; off >>= 1){
            s.x += __shfl_down(s.x, off, 64);
            s.y += __shfl_down(s.y, off, 64);
        }
        if (lane == 0) fbh[0] = s;   // SW(0)=0
    }
    __syncthreads();
    return fbh[0];
}

// ======================= the cooperative mega-kernel =======================
// 64 blocks x 1024 threads. Blocks 0..31: two Lanczos probes per block
// (half h = tid>>9); block 32: CG in both halves (h==1 discards the store).
__global__ __launch_bounds__(1024)
void mega(const float* __restrict__ x, const float* __restrict__ y,
          const float* __restrict__ xn, const float* __restrict__ z,
          float* __restrict__ out,
          float2* __restrict__ d_v, float2* __restrict__ d_rhs, float2* __restrict__ d_wb,
          float* __restrict__ d_al, float* __restrict__ d_be, float* __restrict__ d_nz2,
          float* __restrict__ d_quad, float* __restrict__ d_t1)
{
    __shared__ float2 fb2[2][NFFT];   // 64 KB exactly; scratch carved from dead slots
    cg::grid_group grid = cg::this_grid();
    const int b = blockIdx.x, tid = threadIdx.x;
    const int wid = tid >> 6, lane = tid & 63;

    // ---------------- phase P: build v (3073 cols) and rhs (1537 cols), one wave/col
    if (b == 0 && tid == 0) *d_t1 = 0.f;
    for (int c = b*16 + wid; c < 3073 + MN; c += 1024) {
        bool is_v = c < 3073;
        float pk = is_v ? (float)(c - 1536) : (float)(c - 3073 - 768);
        float sx = 0.f, sy = 0.f;
        if (is_v){
            for (int j = 0; j < 256; ++j){
                float ph = CW * (x[j*64 + lane] * pk);
                float s, cc; __sincosf(ph, &s, &cc);
                sx += cc; sy += s;
            }
        } else {
            for (int j = 0; j < 256; ++j){
                int n = j*64 + lane;
                float yv = y[n];
                float ph = CW * (x[n] * pk);
                float s, cc; __sincosf(ph, &s, &cc);
                sx += cc*yv; sy -= s*yv;
            }
        }
        #pragma unroll
        for (int off = 32; off > 0; off >>= 1){
            sx += __shfl_down(sx, off, 64);
            sy += __shfl_down(sy, off, 64);
        }
        if (lane == 0){
            if (is_v) d_v[c] = make_float2(sx, sy);
            else      d_rhs[c - 3073] = make_float2(sx, sy);
        }
    }
    grid.sync();

    // ---------------- phase S
    if (b < 33) {
        const int h = tid >> 9;
        const int tt = tid & 511;
        float2* fbh = fb2[h];
        Tw T11 = make_tw(-W4096 * (float)tt);
        Tw T8  = make_tw(-W4096 * (float)((tt & 63) << 3));
        Tw T5  = make_tw(-W4096 * (float)((tt & 7)  << 6));
        bool on3 = (tt == 0);
        float w[4];
        w[0] = ws_at(tt); w[1] = ws_at(tt + 512); w[2] = ws_at(tt + 1024);
        w[3] = on3 ? ws_at(1536) : 0.f;

        // build G spectrum into registers g[k] = G at slot 8*tt+k
        float2 g[8];
        #pragma unroll
        for (int k = 0; k < 8; ++k){
            int i = tt + k*512;
            float2 val = make_float2(0.f, 0.f);
            if (i == 0)            val = d_v[1536];
            else if (i <= 1536)    val = d_v[1536 - i];
            else if (i >= 2560)    val = d_v[5632 - i];
            fbh[SW(i)] = val;
        }
        __syncthreads();
        fwd8c<11>(fbh, tt, T11); __syncthreads();
        fwd8c<8 >(fbh, tt, T8);  __syncthreads();
        fwd8c<5 >(fbh, tt, T5);  __syncthreads();
        fwd8_last_reg(fbh, tt, g);
        __syncthreads();   // fb dead before scratch use

        float2 sin_[4], cv[4];
        if (b < 32) {
            // ---------- Lanczos, probe = 2b + h
            const int probe = 2*b + h;
            float2 q[4], qp[4];
            float part = 0.f;
            #pragma unroll
            for (int s = 0; s < 4; ++s){
                float sv = 0.f;
                if (s < 3 || on3){
                    float zv = z[probe*MN + tt + s*512];
                    sv = (zv > 0.f) ? 1.f : ((zv < 0.f) ? -1.f : 0.f);
                }
                q[s] = make_float2(sv, 0.f);
                qp[s] = make_float2(0.f, 0.f);
                part += sv * sv;
            }
            float nz2 = hreduce2(make_float2(part, 0.f), fbh, tt).x;
            if (tt == 0) d_nz2[probe] = nz2;
            float qs = 1.0f / sqrtf(nz2);
            #pragma unroll
            for (int s = 0; s < 4; ++s){ q[s].x *= qs; q[s].y *= qs; }
            float bp = 0.f;
            float cf[4];
            #pragma unroll
            for (int s = 0; s < 4; ++s) cf[s] = w[s] * (10.0f / 4096.0f);
            for (int step = 0; step < 50; ++step) {
                #pragma unroll
                for (int s = 0; s < 4; ++s)
                    sin_[s] = make_float2(w[s]*q[s].x, w[s]*q[s].y);
                conv_fft(fbh, g, tt, T11, T8, T5, sin_, cv);
                float2 v[4];
                float2 pp = make_float2(0.f, 0.f);   // (q.v, v.v)
                #pragma unroll
                for (int s = 0; s < 4; ++s){
                    v[s] = make_float2(q[s].x + cf[s]*cv[s].x - bp*qp[s].x,
                                       q[s].y + cf[s]*cv[s].y - bp*qp[s].y);
                    pp.x += q[s].x*v[s].x + q[s].y*v[s].y;
                    pp.y += v[s].x*v[s].x + v[s].y*v[s].y;
                }
                float2 rr = hreduce2(pp, fbh, tt);
                float alpha = rr.x;
                float beta = sqrtf(fmaxf(rr.y - alpha*alpha, 0.f));
                if (tt == 0) { d_al[probe*50 + step] = alpha; d_be[probe*50 + step] = beta; }
                float binv = 1.0f / fmaxf(beta, 1e-12f);
                #pragma unroll
                for (int s = 0; s < 4; ++s){
                    float2 nq = make_float2((v[s].x - alpha*q[s].x)*binv,
                                            (v[s].y - alpha*q[s].y)*binv);
                    qp[s] = q[s];
                    q[s] = nq;
                }
                bp = beta;
            }
        } else {
            // ---------- CG (both halves identical; h==1 skips the store)
            float2 r[4], p[4], xx[4];
            float part = 0.f;
            #pragma unroll
            for (int s = 0; s < 4; ++s){
                float2 bj = make_float2(0.f, 0.f);
                if (s < 3 || on3){
                    float2 rv = d_rhs[tt + s*512];
                    bj = make_float2(w[s]*rv.x, w[s]*rv.y);
                }
                r[s] = bj; p[s] = bj; xx[s] = make_float2(0.f, 0.f);
                part += bj.x*bj.x + bj.y*bj.y;
            }
            float rs = hreduce2(make_float2(part, 0.f), fbh, tt).x;
            float cf[4];
            #pragma unroll
            for (int s = 0; s < 4; ++s) cf[s] = w[s] * (1.0f / 4096.0f);
            for (int it = 0; it < 50; ++it) {
                #pragma unroll
                for (int s = 0; s < 4; ++s)
                    sin_[s] = make_float2(w[s]*p[s].x, w[s]*p[s].y);
                conv_fft(fbh, g, tt, T11, T8, T5, sin_, cv);
                float2 ap[4];
                part = 0.f;
                #pragma unroll
                for (int s = 0; s < 4; ++s){
                    ap[s] = make_float2(cf[s]*cv[s].x + 0.1f*p[s].x,
                                        cf[s]*cv[s].y + 0.1f*p[s].y);
                    part += p[s].x*ap[s].x + p[s].y*ap[s].y;
                }
                float pAp = hreduce2(make_float2(part, 0.f), fbh, tt).x;
                float a = rs / pAp;
                part = 0.f;
                #pragma unroll
                for (int s = 0; s < 4; ++s){
                    xx[s].x += a*p[s].x; xx[s].y += a*p[s].y;
                    r[s].x -= a*ap[s].x; r[s].y -= a*ap[s].y;
                    part += r[s].x*r[s].x + r[s].y*r[s].y;
                }
                float rsn = hreduce2(make_float2(part, 0.f), fbh, tt).x;
                float sc = rsn / rs;
                #pragma unroll
                for (int s = 0; s < 4; ++s)
                    p[s] = make_float2(r[s].x + sc*p[s].x, r[s].y + sc*p[s].y);
                rs = rsn;
            }
            if (h == 0){
                #pragma unroll
                for (int s = 0; s < 4; ++s){
                    if (s < 3 || on3)
                        d_wb[tt + s*512] = make_float2(w[s]*xx[s].x, w[s]*xx[s].y);
                }
            }
        }
    }
    grid.sync();

    // ---------------- phase T: wave 0 of each block = slq(probe b);
    // waves 1..15 of all blocks = mean rows [0,4096) + t1 rows [4096,20480)
    if (wid == 0) {
        float* sa  = (float*)(&fb2[0][0]);
        float* se  = sa + 64;
        float* se2 = sa + 128;
        int t = lane;
        if (t < 50) {
            sa[t] = d_al[b*50 + t];
            float bv = (t < 49) ? d_be[b*50 + t] : 0.0f;
            se[t] = bv; se2[t] = bv * bv;
        }
        float quad = 0.0f;
        if (t < 50) {
            float lo = 3.4e38f, hi = -3.4e38f;
            for (int i = 0; i < 50; ++i) {
                float rr = ((i > 0) ? fabsf(se[i-1]) : 0.0f) + ((i < 49) ? fabsf(se[i]) : 0.0f);
                lo = fminf(lo, sa[i] - rr);
                hi = fmaxf(hi, sa[i] + rr);
            }
            for (int it = 0; it < 38; ++it) {
                float mid = 0.5f * (lo + hi);
                int cnt = 0;
                float qq = sa[0] - mid;
                cnt += (qq < 0.0f);
                for (int k = 1; k < 50; ++k) {
                    float dnm = (fabsf(qq) < 1e-30f) ? ((qq < 0.0f) ? -1e-30f : 1e-30f) : qq;
                    qq = (sa[k] - mid) - se2[k-1] * __builtin_amdgcn_rcpf(dnm);
                    cnt += (qq < 0.0f);
                }
                if (cnt > t) hi = mid; else lo = mid;
            }
            float lam = 0.5f * (lo + hi);
            float pm = 0.0f, pc = 1.0f, s = 1.0f, bprev = 0.0f;
            for (int k = 0; k < 49; ++k) {
                float bk = fmaxf(se[k], 1e-30f);
                float pn = ((lam - sa[k]) * pc - bprev * pm) * __builtin_amdgcn_rcpf(bk);
                pn = fminf(fmaxf(pn, -1e18f), 1e18f);
                s += pn * pn;
                pm = pc; pc = pn; bprev = bk;
            }
            quad = logf(fmaxf(lam, 1e-18f)) / s;
        }
        #pragma unroll
        for (int off = 32; off > 0; off >>= 1) quad += __shfl_down(quad, off, 64);
        if (t == 0) d_quad[b] = quad * d_nz2[b];
    } else {
        float ta = 0.f;
        for (int r = b*15 + (wid - 1); r < 4096 + 16384; r += 960) {
            bool ismean = r < 4096;
            int n = ismean ? r : (r - 4096);
            float xv = ismean ? xn[n] : x[n];
            float acc = 0.f;
            for (int k = lane; k < MN; k += 64) {
                float ph = CW * (xv * (float)(k - 768));
                float s, c; __sincosf(ph, &s, &c);
                float2 ww = d_wb[k];
                acc += c * ww.x - s * ww.y;
            }
            #pragma unroll
            for (int off = 32; off > 0; off >>= 1) acc += __shfl_down(acc, off, 64);
            if (lane == 0) {
                if (ismean) out[n] = acc;
                else { float yv = y[n]; ta += yv * (yv - acc) * 10.0f; }
            }
        }
        if (lane == 0) atomicAdd(d_t1, ta);
    }
    grid.sync();

    // ---------------- final: lml
    if (b == 0 && tid < 64) {
        float qv = d_quad[tid];
        #pragma unroll
        for (int off = 32; off > 0; off >>= 1) qv += __shfl_down(qv, off, 64);
        if (tid == 0) {
            float ld = qv / 64.0f - 37725.5542f;                    // + N*log(sigma^2)
            out[4096] = -0.5f * (*d_t1) - 0.5f * ld - 15055.8889f;  // - 0.5*N*log(2pi)
        }
    }
}

extern "C" void kernel_launch(void* const* d_in, const int* in_sizes, int n_in,
                              void* d_out, int out_size, void* d_ws, size_t ws_size,
                              hipStream_t stream) {
    const float* d_x  = (const float*)d_in[0];
    const float* d_y  = (const float*)d_in[1];
    const float* d_xn = (const float*)d_in[2];
    const float* d_z  = (const float*)d_in[3];
    float* out = (float*)d_out;
    char* w = (char*)d_ws;
    float2* d_v   = (float2*)(w + 0);       // 3073 c64
    float2* d_rhs = (float2*)(w + 24832);   // 1537 c64
    float2* d_wb  = (float2*)(w + 37376);   // 1537 c64
    float*  d_al  = (float*)(w + 49920);    // 64x50
    float*  d_be  = (float*)(w + 62720);    // 64x50
    float*  d_nz2 = (float*)(w + 75520);    // 64
    float*  d_quad= (float*)(w + 75776);    // 64
    float*  d_t1  = (float*)(w + 76032);    // 1

    void* args[] = { (void*)&d_x, (void*)&d_y, (void*)&d_xn, (void*)&d_z, (void*)&out,
                     (void*)&d_v, (void*)&d_rhs, (void*)&d_wb, (void*)&d_al, (void*)&d_be,
                     (void*)&d_nz2, (void*)&d_quad, (void*)&d_t1 };
    hipLaunchCooperativeKernel((const void*)mega, dim3(64), dim3(1024), args, 0, stream);
}

// Round 8
// 486.082 us; speedup vs baseline: 2.5541x; 2.5541x over previous
//
#include <hip/hip_runtime.h>
#include <hip/hip_cooperative_groups.h>
#include <math.h>

namespace cg = cooperative_groups;

#define MN 1537          // M_NODES
#define NFFT 4096
#define CW 0.06283185307179587f      // 2*pi*h
#define W4096 1.5339807878856412e-3f // 2*pi/4096

__device__ __forceinline__ float2 cmulf(float2 a, float2 b) {
    return make_float2(a.x*b.x - a.y*b.y, a.x*b.y + a.y*b.x);
}
__device__ __forceinline__ float2 cadd(float2 a, float2 b){ return make_float2(a.x+b.x, a.y+b.y); }
__device__ __forceinline__ float2 csub(float2 a, float2 b){ return make_float2(a.x-b.x, a.y-b.y); }
__device__ __forceinline__ float2 mulnegi(float2 z){ return make_float2(z.y, -z.x); }  // z * (-i)
__device__ __forceinline__ float2 mulposi(float2 z){ return make_float2(-z.y, z.x); }  // z * (+i)
__device__ __forceinline__ float2 cconj(float2 z){ return make_float2(z.x, -z.y); }
// XOR bank swizzle: bijective on [0,4096); per-wave bank-pair uniform (4-way min)
// for all stride classes {1,8,64,512} used by the radix-8 stages. No padding.
// [measured r7: SQ_LDS_BANK_CONFLICT 8.02M -> 1.29M vs additive pad]
__device__ __forceinline__ int SW(int i){ return i ^ ((i >> 3) & 15); }

__device__ __forceinline__ float ws_at(int k) {
    float xi = 0.01f * (float)(k - 768);
    float t  = 0.31415926535897931f * xi;      // pi*ell*xi
    float S  = 0.25066282746310002f * expf(-2.0f * t * t); // sqrt(2pi)*ell
    return sqrtf(0.01f * S);
}

// cached twiddle quintet for one fused stage-triple
struct Tw { float2 w1, w2, w4, c1, c3; };

__device__ __forceinline__ Tw make_tw(float ang){
    Tw t;
    __sincosf(ang, &t.w1.y, &t.w1.x);
    t.w2 = cmulf(t.w1, t.w1);
    t.w4 = cmulf(t.w2, t.w2);
    const float R = 0.70710678118654752f;
    t.c1 = cmulf(t.w1, make_float2( R, -R));   // w1 * e^{-i pi/4}
    t.c3 = cmulf(t.w1, make_float2(-R, -R));   // w1 * e^{-i 3pi/4}
    return t;
}

// ---------------- forward DIF triple (stages S, S-1, S-2), cached twiddles
template<int S>
__device__ __forceinline__ void fwd8c(float2* fb, int tt, const Tw& w){
    const int Q = 1 << (S-2);
    const int p = tt & (Q-1);
    const int g = tt >> (S-2);
    const int base = (g << (S+1)) + p;
    float2 a0 = fb[SW(base      )], a1 = fb[SW(base +   Q)];
    float2 a2 = fb[SW(base + 2*Q)], a3 = fb[SW(base + 3*Q)];
    float2 a4 = fb[SW(base + 4*Q)], a5 = fb[SW(base + 5*Q)];
    float2 a6 = fb[SW(base + 6*Q)], a7 = fb[SW(base + 7*Q)];
    float2 b0 = cadd(a0,a4), b1 = cadd(a1,a5), b2 = cadd(a2,a6), b3 = cadd(a3,a7);
    float2 b4 = cmulf(csub(a0,a4), w.w1);
    float2 b5 = cmulf(csub(a1,a5), w.c1);
    float2 b6 = mulnegi(cmulf(csub(a2,a6), w.w1));
    float2 b7 = cmulf(csub(a3,a7), w.c3);
    float2 c0 = cadd(b0,b2), c2 = cmulf(csub(b0,b2), w.w2);
    float2 c1 = cadd(b1,b3), c3 = mulnegi(cmulf(csub(b1,b3), w.w2));
    float2 c4 = cadd(b4,b6), c6 = cmulf(csub(b4,b6), w.w2);
    float2 c5 = cadd(b5,b7), c7 = mulnegi(cmulf(csub(b5,b7), w.w2));
    fb[SW(base      )] = cadd(c0,c1);
    fb[SW(base +   Q)] = cmulf(csub(c0,c1), w.w4);
    fb[SW(base + 2*Q)] = cadd(c2,c3);
    fb[SW(base + 3*Q)] = cmulf(csub(c2,c3), w.w4);
    fb[SW(base + 4*Q)] = cadd(c4,c5);
    fb[SW(base + 5*Q)] = cmulf(csub(c4,c5), w.w4);
    fb[SW(base + 6*Q)] = cadd(c6,c7);
    fb[SW(base + 7*Q)] = cmulf(csub(c6,c7), w.w4);
}

// ---------------- inverse DIT triple (stages S, S+1, S+2), twiddles = conj(cached)
template<int S>
__device__ __forceinline__ void inv8c(float2* fb, int tt, const Tw& w){
    const int Q = 1 << S;
    const int p = tt & (Q-1);
    const int g = tt >> S;
    const int base = (g << (S+3)) + p;
    float2 u1 = cconj(w.w1), u2 = cconj(w.w2), u4 = cconj(w.w4);
    float2 uc1 = cconj(w.c1), uc3 = cconj(w.c3);
    float2 a0 = fb[SW(base      )], a1 = fb[SW(base +   Q)];
    float2 a2 = fb[SW(base + 2*Q)], a3 = fb[SW(base + 3*Q)];
    float2 a4 = fb[SW(base + 4*Q)], a5 = fb[SW(base + 5*Q)];
    float2 a6 = fb[SW(base + 6*Q)], a7 = fb[SW(base + 7*Q)];
    float2 m;
    m = cmulf(a1, u4); float2 t0 = cadd(a0,m), t1 = csub(a0,m);
    m = cmulf(a3, u4); float2 t2 = cadd(a2,m), t3 = csub(a2,m);
    m = cmulf(a5, u4); float2 t4 = cadd(a4,m), t5 = csub(a4,m);
    m = cmulf(a7, u4); float2 t6 = cadd(a6,m), t7 = csub(a6,m);
    m = cmulf(t2, u2);          float2 e0 = cadd(t0,m), e2 = csub(t0,m);
    m = mulposi(cmulf(t3, u2)); float2 e1 = cadd(t1,m), e3 = csub(t1,m);
    m = cmulf(t6, u2);          float2 e4 = cadd(t4,m), e6 = csub(t4,m);
    m = mulposi(cmulf(t7, u2)); float2 e5 = cadd(t5,m), e7 = csub(t5,m);
    m = cmulf(e4, u1);          fb[SW(base      )] = cadd(e0,m); fb[SW(base + 4*Q)] = csub(e0,m);
    m = cmulf(e5, uc1);         fb[SW(base +   Q)] = cadd(e1,m); fb[SW(base + 5*Q)] = csub(e1,m);
    m = mulposi(cmulf(e6, u1)); fb[SW(base + 2*Q)] = cadd(e2,m); fb[SW(base + 6*Q)] = csub(e2,m);
    m = cmulf(e7, uc3);         fb[SW(base + 3*Q)] = cadd(e3,m); fb[SW(base + 7*Q)] = csub(e3,m);
}

// stage-11 triple, inputs from registers (slots tt+s*512; s>=4 are zero)
__device__ __forceinline__ void fwd8_first(float2* fb, int tt, const Tw& w, const float2* in){
    float2 b0 = in[0], b1 = in[1], b2 = in[2], b3 = in[3];
    float2 b4 = cmulf(in[0], w.w1);
    float2 b5 = cmulf(in[1], w.c1);
    float2 b6 = mulnegi(cmulf(in[2], w.w1));
    float2 b7 = cmulf(in[3], w.c3);
    float2 c0 = cadd(b0,b2), c2 = cmulf(csub(b0,b2), w.w2);
    float2 c1 = cadd(b1,b3), c3 = mulnegi(cmulf(csub(b1,b3), w.w2));
    float2 c4 = cadd(b4,b6), c6 = cmulf(csub(b4,b6), w.w2);
    float2 c5 = cadd(b5,b7), c7 = mulnegi(cmulf(csub(b5,b7), w.w2));
    fb[SW(tt       )] = cadd(c0,c1);
    fb[SW(tt +  512)] = cmulf(csub(c0,c1), w.w4);
    fb[SW(tt + 1024)] = cadd(c2,c3);
    fb[SW(tt + 1536)] = cmulf(csub(c2,c3), w.w4);
    fb[SW(tt + 2048)] = cadd(c4,c5);
    fb[SW(tt + 2560)] = cmulf(csub(c4,c5), w.w4);
    fb[SW(tt + 3072)] = cadd(c6,c7);
    fb[SW(tt + 3584)] = cmulf(csub(c6,c7), w.w4);
}

// inverse stage-9 triple returning only slots tt+s*512 (s=0..3) in registers
__device__ __forceinline__ void inv8_last(const float2* fb, int tt, const Tw& w, float2* outv){
    float2 u1 = cconj(w.w1), u2 = cconj(w.w2), u4 = cconj(w.w4);
    float2 uc1 = cconj(w.c1), uc3 = cconj(w.c3);
    float2 a0 = fb[SW(tt       )], a1 = fb[SW(tt +  512)];
    float2 a2 = fb[SW(tt + 1024)], a3 = fb[SW(tt + 1536)];
    float2 a4 = fb[SW(tt + 2048)], a5 = fb[SW(tt + 2560)];
    float2 a6 = fb[SW(tt + 3072)], a7 = fb[SW(tt + 3584)];
    float2 m;
    m = cmulf(a1, u4); float2 t0 = cadd(a0,m), t1 = csub(a0,m);
    m = cmulf(a3, u4); float2 t2 = cadd(a2,m), t3 = csub(a2,m);
    m = cmulf(a5, u4); float2 t4 = cadd(a4,m), t5 = csub(a4,m);
    m = cmulf(a7, u4); float2 t6 = cadd(a6,m), t7 = csub(a6,m);
    m = cmulf(t2, u2);          float2 e0 = cadd(t0,m), e2 = csub(t0,m);
    m = mulposi(cmulf(t3, u2)); float2 e1 = cadd(t1,m), e3 = csub(t1,m);
    m = cmulf(t6, u2);          float2 e4 = cadd(t4,m), e6 = csub(t4,m);
    m = mulposi(cmulf(t7, u2)); float2 e5 = cadd(t5,m), e7 = csub(t5,m);
    outv[0] = cadd(e0, cmulf(e4, u1));
    outv[1] = cadd(e1, cmulf(e5, uc1));
    outv[2] = cadd(e2, mulposi(cmulf(e6, u1)));
    outv[3] = cadd(e3, cmulf(e7, uc3));
}

// fused middle: fwd triple S=2 (identity tw) + pointwise*g + inv triple S=0,
// entirely in registers; touches contiguous slots 8*tt..8*tt+7
__device__ __forceinline__ void mid8(float2* fb, int tt, const float2* g){
    const float R = 0.70710678118654752f;
    const int base = tt << 3;
    float2 a0 = fb[SW(base  )], a1 = fb[SW(base+1)];
    float2 a2 = fb[SW(base+2)], a3 = fb[SW(base+3)];
    float2 a4 = fb[SW(base+4)], a5 = fb[SW(base+5)];
    float2 a6 = fb[SW(base+6)], a7 = fb[SW(base+7)];
    float2 b0 = cadd(a0,a4), b1 = cadd(a1,a5), b2 = cadd(a2,a6), b3 = cadd(a3,a7);
    float2 b4 = csub(a0,a4);
    float2 b5 = cmulf(csub(a1,a5), make_float2( R, -R));
    float2 b6 = mulnegi(csub(a2,a6));
    float2 b7 = cmulf(csub(a3,a7), make_float2(-R, -R));
    float2 c0 = cadd(b0,b2), c2 = csub(b0,b2);
    float2 c1 = cadd(b1,b3), c3 = mulnegi(csub(b1,b3));
    float2 c4 = cadd(b4,b6), c6 = csub(b4,b6);
    float2 c5 = cadd(b5,b7), c7 = mulnegi(csub(b5,b7));
    float2 d0 = cadd(c0,c1), d1 = csub(c0,c1);
    float2 d2 = cadd(c2,c3), d3 = csub(c2,c3);
    float2 d4 = cadd(c4,c5), d5 = csub(c4,c5);
    float2 d6 = cadd(c6,c7), d7 = csub(c6,c7);
    d0 = cmulf(d0, g[0]); d1 = cmulf(d1, g[1]); d2 = cmulf(d2, g[2]); d3 = cmulf(d3, g[3]);
    d4 = cmulf(d4, g[4]); d5 = cmulf(d5, g[5]); d6 = cmulf(d6, g[6]); d7 = cmulf(d7, g[7]);
    float2 m;
    m = d1; float2 t0 = cadd(d0,m), t1 = csub(d0,m);
    m = d3; float2 t2 = cadd(d2,m), t3 = csub(d2,m);
    m = d5; float2 t4 = cadd(d4,m), t5 = csub(d4,m);
    m = d7; float2 t6 = cadd(d6,m), t7 = csub(d6,m);
    m = t2;          float2 e0 = cadd(t0,m), e2 = csub(t0,m);
    m = mulposi(t3); float2 e1 = cadd(t1,m), e3 = csub(t1,m);
    m = t6;          float2 e4 = cadd(t4,m), e6 = csub(t4,m);
    m = mulposi(t7); float2 e5 = cadd(t5,m), e7 = csub(t5,m);
    m = e4;                           fb[SW(base  )] = cadd(e0,m); fb[SW(base+4)] = csub(e0,m);
    m = cmulf(e5, make_float2(R, R)); fb[SW(base+1)] = cadd(e1,m); fb[SW(base+5)] = csub(e1,m);
    m = mulposi(e6);                  fb[SW(base+2)] = cadd(e2,m); fb[SW(base+6)] = csub(e2,m);
    m = cmulf(e7, make_float2(-R, R));fb[SW(base+3)] = cadd(e3,m); fb[SW(base+7)] = csub(e3,m);
}

// fwd S=2 triple with register outputs only (for G spectrum capture)
__device__ __forceinline__ void fwd8_last_reg(const float2* fb, int tt, float2* gout){
    const float R = 0.70710678118654752f;
    const int base = tt << 3;
    float2 a0 = fb[SW(base  )], a1 = fb[SW(base+1)];
    float2 a2 = fb[SW(base+2)], a3 = fb[SW(base+3)];
    float2 a4 = fb[SW(base+4)], a5 = fb[SW(base+5)];
    float2 a6 = fb[SW(base+6)], a7 = fb[SW(base+7)];
    float2 b0 = cadd(a0,a4), b1 = cadd(a1,a5), b2 = cadd(a2,a6), b3 = cadd(a3,a7);
    float2 b4 = csub(a0,a4);
    float2 b5 = cmulf(csub(a1,a5), make_float2( R, -R));
    float2 b6 = mulnegi(csub(a2,a6));
    float2 b7 = cmulf(csub(a3,a7), make_float2(-R, -R));
    float2 c0 = cadd(b0,b2), c2 = csub(b0,b2);
    float2 c1 = cadd(b1,b3), c3 = mulnegi(csub(b1,b3));
    float2 c4 = cadd(b4,b6), c6 = csub(b4,b6);
    float2 c5 = cadd(b5,b7), c7 = mulnegi(csub(b5,b7));
    gout[0] = cadd(c0,c1); gout[1] = csub(c0,c1);
    gout[2] = cadd(c2,c3); gout[3] = csub(c2,c3);
    gout[4] = cadd(c4,c5); gout[5] = csub(c4,c5);
    gout[6] = cadd(c6,c7); gout[7] = csub(c6,c7);
}

// circular convolution; result scaled by 4096
__device__ __forceinline__ void conv_fft(float2* fb, const float2* g, int tt,
                                         const Tw& T11, const Tw& T8, const Tw& T5,
                                         const float2* in, float2* outv){
    __syncthreads();                       // prior reads of fb done
    fwd8_first(fb, tt, T11, in); __syncthreads();
    fwd8c<8>(fb, tt, T8); __syncthreads();
    fwd8c<5>(fb, tt, T5); __syncthreads();
    mid8(fb, tt, g);      __syncthreads();
    inv8c<3>(fb, tt, T5); __syncthreads();
    inv8c<6>(fb, tt, T8); __syncthreads();
    inv8_last(fb, tt, T11, outv);
}

// ---------------- block reductions (512 threads = 8 waves), result to all
__device__ float block_reduce8(float v, volatile float* sc) {
    int lane = threadIdx.x & 63, wid = threadIdx.x >> 6;
    #pragma unroll
    for (int off = 32; off > 0; off >>= 1) v += __shfl_down(v, off, 64);
    if (lane == 0) sc[wid] = v;
    __syncthreads();
    if (wid == 0) {
        float s = (lane < 8) ? sc[lane] : 0.0f;
        #pragma unroll
        for (int off = 4; off > 0; off >>= 1) s += __shfl_down(s, off, 64);
        if (lane == 0) sc[16] = s;
    }
    __syncthreads();
    return sc[16];
}

__device__ float2 block_reduce2(float2 v, volatile float* sc) {
    int lane = threadIdx.x & 63, wid = threadIdx.x >> 6;
    #pragma unroll
    for (int off = 32; off > 0; off >>= 1) {
        v.x += __shfl_down(v.x, off, 64);
        v.y += __shfl_down(v.y, off, 64);
    }
    if (lane == 0) { sc[wid] = v.x; sc[17 + wid] = v.y; }
    __syncthreads();
    if (wid == 0) {
        float sx = (lane < 8) ? sc[lane] : 0.0f;
        float sy = (lane < 8) ? sc[17 + lane] : 0.0f;
        #pragma unroll
        for (int off = 4; off > 0; off >>= 1) {
            sx += __shfl_down(sx, off, 64);
            sy += __shfl_down(sy, off, 64);
        }
        if (lane == 0) { sc[16] = sx; sc[33] = sy; }
    }
    __syncthreads();
    return make_float2(sc[16], sc[33]);
}

// ======================= the cooperative mega-kernel =======================
__global__ __launch_bounds__(512) __attribute__((amdgpu_waves_per_eu(2, 2)))
void mega(const float* __restrict__ x, const float* __restrict__ y,
          const float* __restrict__ xn, const float* __restrict__ z,
          float* __restrict__ out,
          float2* __restrict__ d_v, float2* __restrict__ d_rhs, float2* __restrict__ d_wb,
          float* __restrict__ d_al, float* __restrict__ d_be, float* __restrict__ d_nz2,
          float* __restrict__ d_quad, float* __restrict__ d_t1p)
{
    __shared__ float2 fb[NFFT];    // 32 KB, XOR-swizzled, no pad
    __shared__ float  redb[40];
    cg::grid_group grid = cg::this_grid();
    const int b = blockIdx.x, tid = threadIdx.x;
    const int wid = tid >> 6, lane = tid & 63;

    // ---------------- phase P: build v (3073 cols) and rhs (1537 cols), one wave per col
    for (int c = b*8 + wid; c < 3073 + MN; c += 2048) {
        bool is_v = c < 3073;
        float pk = is_v ? (float)(c - 1536) : (float)(c - 3073 - 768);
        float sx = 0.f, sy = 0.f;
        if (is_v){
            for (int j = 0; j < 256; ++j){
                float ph = CW * (x[j*64 + lane] * pk);
                float s, cc; __sincosf(ph, &s, &cc);
                sx += cc; sy += s;
            }
        } else {
            for (int j = 0; j < 256; ++j){
                int n = j*64 + lane;
                float yv = y[n];
                float ph = CW * (x[n] * pk);
                float s, cc; __sincosf(ph, &s, &cc);
                sx += cc*yv; sy -= s*yv;
            }
        }
        #pragma unroll
        for (int off = 32; off > 0; off >>= 1){
            sx += __shfl_down(sx, off, 64);
            sy += __shfl_down(sy, off, 64);
        }
        if (lane == 0){
            if (is_v) d_v[c] = make_float2(sx, sy);
            else      d_rhs[c - 3073] = make_float2(sx, sy);
        }
    }
    grid.sync();

    // ---------------- phase S: blocks 0..63 Lanczos, block 64 CG
    if (b < 65) {
        Tw T11 = make_tw(-W4096 * (float)tid);
        Tw T8  = make_tw(-W4096 * (float)((tid & 63) << 3));
        Tw T5  = make_tw(-W4096 * (float)((tid & 7)  << 6));
        bool on3 = (tid == 0);
        float w[4];
        w[0] = ws_at(tid); w[1] = ws_at(tid + 512); w[2] = ws_at(tid + 1024);
        w[3] = on3 ? ws_at(1536) : 0.f;

        // build G spectrum into registers g[k] = G at slot 8*tid+k
        float2 g[8];
        #pragma unroll
        for (int k = 0; k < 8; ++k){
            int i = tid + k*512;
            float2 val = make_float2(0.f, 0.f);
            if (i == 0)            val = d_v[1536];
            else if (i <= 1536)    val = d_v[1536 - i];
            else if (i >= 2560)    val = d_v[5632 - i];
            fb[SW(i)] = val;
        }
        __syncthreads();
        fwd8c<11>(fb, tid, T11); __syncthreads();
        fwd8c<8 >(fb, tid, T8);  __syncthreads();
        fwd8c<5 >(fb, tid, T5);  __syncthreads();
        fwd8_last_reg(fb, tid, g);

        float2 sin_[4], cv[4];
        if (b < 64) {
            // ---------- Lanczos (fused dual reduction: beta^2 = |v|^2 - alpha^2)
            float2 q[4], qp[4];
            float part = 0.f;
            #pragma unroll
            for (int s = 0; s < 4; ++s){
                float sv = 0.f;
                if (s < 3 || on3){
                    float zv = z[b*MN + tid + s*512];
                    sv = (zv > 0.f) ? 1.f : ((zv < 0.f) ? -1.f : 0.f);
                }
                q[s] = make_float2(sv, 0.f);
                qp[s] = make_float2(0.f, 0.f);
                part += sv * sv;
            }
            float nz2 = block_reduce8(part, redb);
            if (tid == 0) d_nz2[b] = nz2;
            float qs = 1.0f / sqrtf(nz2);
            #pragma unroll
            for (int s = 0; s < 4; ++s){ q[s].x *= qs; q[s].y *= qs; }
            float bp = 0.f;
            float cf[4];
            #pragma unroll
            for (int s = 0; s < 4; ++s) cf[s] = w[s] * (10.0f / 4096.0f);
            for (int step = 0; step < 50; ++step) {
                #pragma unroll
                for (int s = 0; s < 4; ++s)
                    sin_[s] = make_float2(w[s]*q[s].x, w[s]*q[s].y);
                conv_fft(fb, g, tid, T11, T8, T5, sin_, cv);
                float2 v[4];
                float2 pp = make_float2(0.f, 0.f);   // (q.v, v.v)
                #pragma unroll
                for (int s = 0; s < 4; ++s){
                    v[s] = make_float2(q[s].x + cf[s]*cv[s].x - bp*qp[s].x,
                                       q[s].y + cf[s]*cv[s].y - bp*qp[s].y);
                    pp.x += q[s].x*v[s].x + q[s].y*v[s].y;
                    pp.y += v[s].x*v[s].x + v[s].y*v[s].y;
                }
                float2 rr = block_reduce2(pp, redb);
                float alpha = rr.x;
                float beta = sqrtf(fmaxf(rr.y - alpha*alpha, 0.f));
                if (tid == 0) { d_al[b*50 + step] = alpha; d_be[b*50 + step] = beta; }
                float binv = 1.0f / fmaxf(beta, 1e-12f);
                #pragma unroll
                for (int s = 0; s < 4; ++s){
                    float2 nq = make_float2((v[s].x - alpha*q[s].x)*binv,
                                            (v[s].y - alpha*q[s].y)*binv);
                    qp[s] = q[s];
                    q[s] = nq;
                }
                bp = beta;
            }
        } else {
            // ---------- CG (classic two reductions; off critical path)
            float2 r[4], p[4], xx[4];
            float part = 0.f;
            #pragma unroll
            for (int s = 0; s < 4; ++s){
                float2 bj = make_float2(0.f, 0.f);
                if (s < 3 || on3){
                    float2 rv = d_rhs[tid + s*512];
                    bj = make_float2(w[s]*rv.x, w[s]*rv.y);
                }
                r[s] = bj; p[s] = bj; xx[s] = make_float2(0.f, 0.f);
                part += bj.x*bj.x + bj.y*bj.y;
            }
            float rs = block_reduce8(part, redb);
            float cf[4];
            #pragma unroll
            for (int s = 0; s < 4; ++s) cf[s] = w[s] * (1.0f / 4096.0f);
            for (int it = 0; it < 50; ++it) {
                #pragma unroll
                for (int s = 0; s < 4; ++s)
                    sin_[s] = make_float2(w[s]*p[s].x, w[s]*p[s].y);
                conv_fft(fb, g, tid, T11, T8, T5, sin_, cv);
                float2 ap[4];
                part = 0.f;
                #pragma unroll
                for (int s = 0; s < 4; ++s){
                    ap[s] = make_float2(cf[s]*cv[s].x + 0.1f*p[s].x,
                                        cf[s]*cv[s].y + 0.1f*p[s].y);
                    part += p[s].x*ap[s].x + p[s].y*ap[s].y;
                }
                float pAp = block_reduce8(part, redb);
                float a = rs / pAp;
                part = 0.f;
                #pragma unroll
                for (int s = 0; s < 4; ++s){
                    xx[s].x += a*p[s].x; xx[s].y += a*p[s].y;
                    r[s].x -= a*ap[s].x; r[s].y -= a*ap[s].y;
                    part += r[s].x*r[s].x + r[s].y*r[s].y;
                }
                float rsn = block_reduce8(part, redb);
                float sc = rsn / rs;
                #pragma unroll
                for (int s = 0; s < 4; ++s)
                    p[s] = make_float2(r[s].x + sc*p[s].x, r[s].y + sc*p[s].y);
                rs = rsn;
            }
            #pragma unroll
            for (int s = 0; s < 4; ++s){
                if (s < 3 || on3)
                    d_wb[tid + s*512] = make_float2(w[s]*xx[s].x, w[s]*xx[s].y);
            }
        }
    }
    grid.sync();

    // ---------------- phase T: slq (blocks 0-63) | mean (64-95) | t1 (96-223)
    if (b < 64) {
        if (tid < 64) {
            float* sa  = (float*)fb;       // a[64] | e[64] | e2[64]
            float* se  = sa + 64;
            float* se2 = sa + 128;
            int t = tid;
            if (t < 50) {
                sa[t] = d_al[b*50 + t];
                float bv = (t < 49) ? d_be[b*50 + t] : 0.0f;
                se[t] = bv; se2[t] = bv * bv;
            }
            float quad = 0.0f;
            if (t < 50) {
                float lo = 3.4e38f, hi = -3.4e38f;
                for (int i = 0; i < 50; ++i) {
                    float rr = ((i > 0) ? fabsf(se[i-1]) : 0.0f) + ((i < 49) ? fabsf(se[i]) : 0.0f);
                    lo = fminf(lo, sa[i] - rr);
                    hi = fmaxf(hi, sa[i] + rr);
                }
                for (int it = 0; it < 38; ++it) {
                    float mid = 0.5f * (lo + hi);
                    int cnt = 0;
                    float qq = sa[0] - mid;
                    cnt += (qq < 0.0f);
                    for (int k = 1; k < 50; ++k) {
                        float dnm = (fabsf(qq) < 1e-30f) ? ((qq < 0.0f) ? -1e-30f : 1e-30f) : qq;
                        qq = (sa[k] - mid) - se2[k-1] * __builtin_amdgcn_rcpf(dnm);
                        cnt += (qq < 0.0f);
                    }
                    if (cnt > t) hi = mid; else lo = mid;
                }
                float lam = 0.5f * (lo + hi);
                float pm = 0.0f, pc = 1.0f, s = 1.0f, bprev = 0.0f;
                for (int k = 0; k < 49; ++k) {
                    float bk = fmaxf(se[k], 1e-30f);
                    float pn = ((lam - sa[k]) * pc - bprev * pm) * __builtin_amdgcn_rcpf(bk);
                    pn = fminf(fmaxf(pn, -1e18f), 1e18f);
                    s += pn * pn;
                    pm = pc; pc = pn; bprev = bk;
                }
                quad = logf(fmaxf(lam, 1e-18f)) / s;
            }
            #pragma unroll
            for (int off = 32; off > 0; off >>= 1) quad += __shfl_down(quad, off, 64);
            if (t == 0) d_quad[b] = quad * d_nz2[b];
        }
    } else if (b < 96) {
        int row = (b - 64)*128 + (tid >> 2);
        int sub = tid & 3;
        float xv = xn[row];
        float acc = 0.f;
        for (int k = sub; k < MN; k += 4) {
            float ph = CW * (xv * (float)(k - 768));
            float s, c; __sincosf(ph, &s, &c);
            float2 ww = d_wb[k];
            acc += c * ww.x - s * ww.y;
        }
        acc += __shfl_down(acc, 2, 4);
        acc += __shfl_down(acc, 1, 4);
        if (sub == 0) out[row] = acc;
    } else if (b < 224) {
        int n = (b - 96)*128 + (tid >> 2);
        int sub = tid & 3;
        float xv = x[n], yv = y[n];
        float acc = 0.f;
        for (int k = sub; k < MN; k += 4) {
            float ph = CW * (xv * (float)(k - 768));
            float s, c; __sincosf(ph, &s, &c);
            float2 ww = d_wb[k];
            acc += c * ww.x - s * ww.y;
        }
        acc += __shfl_down(acc, 2, 4);
        acc += __shfl_down(acc, 1, 4);
        float contrib = (sub == 0) ? yv * (yv - acc) * 10.0f : 0.f;
        #pragma unroll
        for (int off = 32; off > 0; off >>= 1) contrib += __shfl_down(contrib, off, 64);
        if (lane == 0) redb[wid] = contrib;
        __syncthreads();
        if (tid == 0) {
            float s = 0.f;
            #pragma unroll
            for (int i = 0; i < 8; ++i) s += redb[i];
            d_t1p[b - 96] = s;
        }
    }
    grid.sync();

    // ---------------- final: lml
    if (b == 0 && tid < 64) {
        float qv = d_quad[tid];
        float t1 = d_t1p[tid] + d_t1p[tid + 64];
        #pragma unroll
        for (int off = 32; off > 0; off >>= 1) {
            qv += __shfl_down(qv, off, 64);
            t1 += __shfl_down(t1, off, 64);
        }
        if (tid == 0) {
            float ld = qv / 64.0f - 37725.5542f;              // + N*log(sigma^2)
            out[4096] = -0.5f * t1 - 0.5f * ld - 15055.8889f; // - 0.5*N*log(2pi)
        }
    }
}

extern "C" void kernel_launch(void* const* d_in, const int* in_sizes, int n_in,
                              void* d_out, int out_size, void* d_ws, size_t ws_size,
                              hipStream_t stream) {
    const float* d_x  = (const float*)d_in[0];
    const float* d_y  = (const float*)d_in[1];
    const float* d_xn = (const float*)d_in[2];
    const float* d_z  = (const float*)d_in[3];
    float* out = (float*)d_out;
    char* w = (char*)d_ws;
    float2* d_v   = (float2*)(w + 0);       // 3073 c64
    float2* d_rhs = (float2*)(w + 24832);   // 1537 c64
    float2* d_wb  = (float2*)(w + 37376);   // 1537 c64
    float*  d_al  = (float*)(w + 49920);    // 64x50
    float*  d_be  = (float*)(w + 62720);    // 64x50
    float*  d_nz2 = (float*)(w + 75520);    // 64
    float*  d_quad= (float*)(w + 75776);    // 64
    float*  d_t1p = (float*)(w + 76032);    // 128

    void* args[] = { (void*)&d_x, (void*)&d_y, (void*)&d_xn, (void*)&d_z, (void*)&out,
                     (void*)&d_v, (void*)&d_rhs, (void*)&d_wb, (void*)&d_al, (void*)&d_be,
                     (void*)&d_nz2, (void*)&d_quad, (void*)&d_t1p };
    hipLaunchCooperativeKernel((const void*)mega, dim3(256), dim3(512), args, 0, stream);
}